// Round 2
// baseline (464.068 us; speedup 1.0000x reference)
//
#include <hip/hip_runtime.h>
#include <cstddef>

#define NN 10
#define NB 512
#define NP 1152
#define CI 8
#define CO 16
#define BLOCK 512     // 8 waves
#define BT 4          // batches per block
#define NPER 5        // n's per block (n-split = 2)
#define PSLOTS 128    // BLOCK/4 p-slots
#define PT 9          // NP / PSLOTS
#define NWAVE 8

// LDS layout (floats)
#define X_FLOATS (BT * NP * CI)                  // 36864 (147456 B)
#define SRED_OFF (X_FLOATS)                      // [NWAVE][BT][CO] = 512
#define ZRED_OFF (SRED_OFF + NWAVE * BT * CO)    // [NWAVE][BT] = 32
#define MZ_OFF   (ZRED_OFF + NWAVE * BT)         // [NWAVE][BT] = 32
#define VBUF_OFF (MZ_OFF + NWAVE * BT)           // [BT][CO] = 64
#define SMEM_FLOATS (VBUF_OFF + BT * CO)
#define SMEM_BYTES (SMEM_FLOATS * 4)             // 150016 B < 160 KiB

__global__
__attribute__((amdgpu_flat_work_group_size(BLOCK, BLOCK), amdgpu_waves_per_eu(2, 2)))
void caps_kernel(const float* __restrict__ x, const float* __restrict__ W,
                 float* __restrict__ out) {
  extern __shared__ float smem[];
  float4* X4 = (float4*)smem;

  const int tid  = threadIdx.x;
  const int lane = tid & 63;
  const int wid  = tid >> 6;
  const int o4   = (tid & 3) << 2;   // owned o-quad start
  const int ps   = tid >> 2;         // p-slot 0..127

  const int bid = blockIdx.x;
  const int nh  = bid & 1;           // n-half; same-XCD blocks share nh (bid%8 parity)
  const int b0  = (bid >> 1) * BT;

  // ---- stage x[b0..b0+3] into LDS, XOR-swizzled at float4 granularity ----
  // chunk j = (b*NP+p)*2 + h  ->  LDS chunk j ^ bit2(p) = j ^ ((j>>3)&1)
  {
    const float4* xg = (const float4*)(x + (size_t)b0 * NP * CI);
#pragma unroll
    for (int k = 0; k < 18; ++k) {
      const int j = tid + BLOCK * k;          // 9216 float4 total
      X4[j ^ ((j >> 3) & 1)] = xg[j];
    }
  }
  __syncthreads();

  for (int ni = 0; ni < NPER; ++ni) {
    const int n = nh * NPER + ni;
    const float* Wn = W + ((size_t)n * NP + ps) * (CI * CO) + o4;

    float4 u[BT][PT];   // 144 VGPRs
    float  bl[BT][PT];  // 36 VGPRs

    // ---------------- u-build: u[b][k][o4..o4+3] = sum_i x[b,p,i] W[n,p,i,o] ----------------
#pragma unroll
    for (int k = 0; k < PT; ++k) {
      const int p = ps + PSLOTS * k;
      const float* wrow = Wn + (size_t)k * (PSLOTS * CI * CO);
      float4 wv[CI];
#pragma unroll
      for (int i = 0; i < CI; ++i) wv[i] = *(const float4*)(wrow + i * CO);
      const int sw = (p >> 2) & 1;
#pragma unroll
      for (int b = 0; b < BT; ++b) {
        const int c0 = (b * NP + p) << 1;
        float xi[CI];
        *(float4*)&xi[0] = X4[c0 ^ sw];
        *(float4*)&xi[4] = X4[(c0 | 1) ^ sw];
        float4 a = make_float4(0.f, 0.f, 0.f, 0.f);
#pragma unroll
        for (int i = 0; i < CI; ++i) {
          a.x = fmaf(xi[i], wv[i].x, a.x);
          a.y = fmaf(xi[i], wv[i].y, a.y);
          a.z = fmaf(xi[i], wv[i].z, a.z);
          a.w = fmaf(xi[i], wv[i].w, a.w);
        }
        u[b][k] = a;
        bl[b][k] = 0.f;
      }
    }

    float4 vvb[BT];
    float  mm[BT];

    // ---------------- routing (3 iters) ----------------
#pragma unroll 1
    for (int it = 0; it < 3; ++it) {
      if (it > 0) {
        // a = u . v  (reduce over 16 o = 4 lanes x 4 comps); bl += a; wave-max
#pragma unroll
        for (int b = 0; b < BT; ++b) {
          float m = -1e30f;
#pragma unroll
          for (int k = 0; k < PT; ++k) {
            float d = u[b][k].x * vvb[b].x + u[b][k].y * vvb[b].y
                    + u[b][k].z * vvb[b].z + u[b][k].w * vvb[b].w;
            d += __shfl_xor(d, 1);
            d += __shfl_xor(d, 2);
            const float nb2 = bl[b][k] + d;
            bl[b][k] = nb2;
            m = fmaxf(m, nb2);
          }
#pragma unroll
          for (int s = 4; s <= 32; s <<= 1) m = fmaxf(m, __shfl_xor(m, s));
          if (lane == 0) smem[MZ_OFF + wid * BT + b] = m;
        }
        __syncthreads();
#pragma unroll
        for (int b = 0; b < BT; ++b) {
          float m = smem[MZ_OFF + b];
#pragma unroll
          for (int w = 1; w < NWAVE; ++w) m = fmaxf(m, smem[MZ_OFF + w * BT + b]);
          mm[b] = m;
        }
      }

      // s-pass: S = sum_p e*u, Z = sum_p e   (e = 1 at it==0)
#pragma unroll
      for (int b = 0; b < BT; ++b) {
        float z = 0.f;
        float4 ps4 = make_float4(0.f, 0.f, 0.f, 0.f);
        if (it == 0) {
#pragma unroll
          for (int k = 0; k < PT; ++k) {
            z += 1.f;
            ps4.x += u[b][k].x; ps4.y += u[b][k].y;
            ps4.z += u[b][k].z; ps4.w += u[b][k].w;
          }
        } else {
#pragma unroll
          for (int k = 0; k < PT; ++k) {
            const float e = __expf(bl[b][k] - mm[b]);
            z += e;
            ps4.x = fmaf(e, u[b][k].x, ps4.x);
            ps4.y = fmaf(e, u[b][k].y, ps4.y);
            ps4.z = fmaf(e, u[b][k].z, ps4.z);
            ps4.w = fmaf(e, u[b][k].w, ps4.w);
          }
        }
#pragma unroll
        for (int s = 4; s <= 32; s <<= 1) {
          ps4.x += __shfl_xor(ps4.x, s);
          ps4.y += __shfl_xor(ps4.y, s);
          ps4.z += __shfl_xor(ps4.z, s);
          ps4.w += __shfl_xor(ps4.w, s);
          z     += __shfl_xor(z, s);
        }
        if (lane < 4)  *(float4*)&smem[SRED_OFF + (wid * BT + b) * CO + (lane << 2)] = ps4;
        if (lane == 0) smem[ZRED_OFF + wid * BT + b] = z;
      }
      __syncthreads();

      // finalize: 64 threads -> s = S/Z, squash, broadcast/store
      if (tid < 64) {
        const int b = tid >> 4, o = tid & 15;
        float s = 0.f, Z = 0.f;
#pragma unroll
        for (int w = 0; w < NWAVE; ++w) {
          s += smem[SRED_OFF + (w * BT + b) * CO + o];
          Z += smem[ZRED_OFF + w * BT + b];
        }
        s /= Z;
        float sq = s * s;
#pragma unroll
        for (int m2 = 1; m2 <= 8; m2 <<= 1) sq += __shfl_xor(sq, m2);
        const float nrm = sqrtf(sq);
        const float vj  = s * (nrm / (1.f + sq));
        if (it == 2) out[((size_t)n * NB + b0 + b) * CO + o] = vj;
        else         smem[VBUF_OFF + b * CO + o] = vj;
      }
      if (it < 2) {
        __syncthreads();
#pragma unroll
        for (int b = 0; b < BT; ++b)
          vvb[b] = *(const float4*)&smem[VBUF_OFF + b * CO + o4];
      }
    }
    __syncthreads();  // protect sred/mz reuse across n iterations
  }
}

extern "C" void kernel_launch(void* const* d_in, const int* in_sizes, int n_in,
                              void* d_out, int out_size, void* d_ws, size_t ws_size,
                              hipStream_t stream) {
  const float* x = (const float*)d_in[0];
  const float* W = (const float*)d_in[1];
  float* out     = (float*)d_out;
  (void)in_sizes; (void)n_in; (void)out_size; (void)d_ws; (void)ws_size;

  // allow >64 KiB dynamic LDS (idempotent, host-side; safe under graph capture)
  hipFuncSetAttribute((const void*)caps_kernel,
                      hipFuncAttributeMaxDynamicSharedMemorySize, SMEM_BYTES);

  const int grid = (NB / BT) * 2;  // 256 blocks: (b-group, n-half)
  caps_kernel<<<grid, BLOCK, SMEM_BYTES, stream>>>(x, W, out);
}